// Round 8
// baseline (153.306 us; speedup 1.0000x reference)
//
#include <hip/hip_runtime.h>
#include <stdint.h>

typedef int i32x4 __attribute__((ext_vector_type(4)));
typedef int i32x16 __attribute__((ext_vector_type(16)));
typedef short s16x8 __attribute__((ext_vector_type(8)));
typedef unsigned long long ull;

#define BB 16384
#define KD 784
#define KP 896  // padded to multiple of 128 (BK=128)
#define N1 1024
#define N2 10
#define NTOT (BB * N2)  // 163840

// ---- workspace layout (bytes) ----
#define OFF_AQ 0ULL
#define SZ_AQ (14680064ULL)  // 16384*896 i8
#define OFF_W1Q (OFF_AQ + SZ_AQ)
#define SZ_W1Q (917504ULL)  // 1024*896 i8
#define OFF_W2Q (OFF_W1Q + SZ_W1Q)
#define SZ_W2Q (16384ULL)  // 16*1024 i8 (rows 10..15 poison; masked downstream)
#define OFF_C1 (OFF_W2Q + SZ_W2Q)
#define SZ_C1 (33554432ULL)  // 16384*1024 i16
#define OFF_STATS (OFF_C1 + SZ_C1)
#define SZ_STATS (16384ULL)
// stats sublayout (bytes): colsum int[1024] @0; colsq ull[1024] @4096;
//   sum2p int stride 16 ints (64B), 16 entries @12288;
//   sq2p  ull stride 8 ulls (64B), 16 entries @13312;
//   gsum int @14336; gsq int @14400  (separate cache lines)
#define OFF_C2 (OFF_STATS + SZ_STATS)
#define SZ_C2 (524288ULL)  // 16384*16 i16 (padded cols)
#define OFF_T2 (OFF_C2 + SZ_C2)
#define SZ_T2 (163840ULL)  // i8

__device__ __forceinline__ void async16(const void* g, void* l) {
  __builtin_amdgcn_global_load_lds((__attribute__((address_space(1))) void*)(void*)(g),
                                   (__attribute__((address_space(3))) void*)(l), 16, 0, 0);
}

__device__ __forceinline__ int8_t ternq(float v) {
  float q = rintf(v);
  return q > 0.5f ? 1 : (q < -0.5f ? -1 : 0);
}

// K0: quantize x -> Aq (i8, K padded to 896), W1 -> W1q, W2 -> W2q; zero stats region.
__global__ void k0_quant(const float* __restrict__ x, const float* __restrict__ W1,
                         const float* __restrict__ W2, int8_t* __restrict__ Aq,
                         int8_t* __restrict__ W1q, int8_t* __restrict__ W2q,
                         int* __restrict__ stats) {
  const int TA = BB * KP / 16;  // 917504
  const int TW = N1 * KP / 16;  // 57344
  const int T2 = N2 * N1 / 16;  // 640
  int tid = blockIdx.x * 256 + threadIdx.x;
  if (tid < 4096) stats[tid] = 0;  // 16KB stats zeroed (runs before k1 in stream order)
  union {
    int4 v;
    int8_t b[16];
  } o;
  o.v = make_int4(0, 0, 0, 0);
  if (tid < TA) {
    int base = tid * 16;
    int r = base / KP, k = base - r * KP;
    if (k < KD) {
      const float4* xp = (const float4*)&x[r * KD + k];
#pragma unroll
      for (int g = 0; g < 4; ++g) {
        float4 f = xp[g];
        o.b[g * 4 + 0] = ternq(2.0f * f.x - 1.0f);
        o.b[g * 4 + 1] = ternq(2.0f * f.y - 1.0f);
        o.b[g * 4 + 2] = ternq(2.0f * f.z - 1.0f);
        o.b[g * 4 + 3] = ternq(2.0f * f.w - 1.0f);
      }
    }
    *(int4*)&Aq[base] = o.v;
  } else if (tid < TA + TW) {
    int base = (tid - TA) * 16;
    int r = base / KP, k = base - r * KP;
    if (k < KD) {
      const float4* wp = (const float4*)&W1[r * KD + k];
#pragma unroll
      for (int g = 0; g < 4; ++g) {
        float4 f = wp[g];
        o.b[g * 4 + 0] = ternq(f.x);
        o.b[g * 4 + 1] = ternq(f.y);
        o.b[g * 4 + 2] = ternq(f.z);
        o.b[g * 4 + 3] = ternq(f.w);
      }
    }
    *(int4*)&W1q[base] = o.v;
  } else if (tid < TA + TW + T2) {
    int base = (tid - TA - TW) * 16;
    const float4* wp = (const float4*)&W2[base];
#pragma unroll
    for (int g = 0; g < 4; ++g) {
      float4 f = wp[g];
      o.b[g * 4 + 0] = ternq(f.x);
      o.b[g * 4 + 1] = ternq(f.y);
      o.b[g * 4 + 2] = ternq(f.z);
      o.b[g * 4 + 3] = ternq(f.w);
    }
    *(int4*)&W2q[base] = o.v;
  }
}

// K1: C1 = Aq @ W1q^T (64x256 tile, BK=128, i8 MFMA 32x32x32) + fused col stats.
// Wider tile: A-panel re-fetch drops 8 -> 4 passes (117 -> 59 MB of L2-fill traffic).
// LDS 43KB/block -> 3 blocks/CU. Each wave: 32 rows x 128 cols = 4 accs of 32x32.
// A/B frag: m=lane&31, k=(lane>>5)*16+j. C/D: col=lane&31,
// row=(reg&3)+8*(reg>>2)+4*(lane>>5)  [HW-verified, dtype-indep].
__global__ __launch_bounds__(256, 3) void k1_gemm1(const int8_t* __restrict__ Aq,
                                                   const int8_t* __restrict__ W1q,
                                                   short* __restrict__ C1,
                                                   int* __restrict__ colsum,
                                                   ull* __restrict__ colsq) {
  __shared__ int8_t As[64 * 128];
  __shared__ int8_t Bs[256 * 128];
  __shared__ int cS[256];
  __shared__ int cQ[256];
  const int t = threadIdx.x;
  const int lane = t & 63, wave = t >> 6;
  const int wr = wave >> 1, wc = wave & 1;  // wave = 32-row half x 128-col half
  const int rowBase = blockIdx.y * 64, colBase = blockIdx.x * 256;
  cS[t] = 0;
  cQ[t] = 0;

  i32x16 acc[4] = {};
  const int m32 = lane & 31, kg = lane >> 5;

  for (int kt = 0; kt < 7; ++kt) {
    __syncthreads();
    const int kb = kt * 128;
    // stage A: 512 chunks (rows 0..63), 2 per thread; granule swizzle g = pos ^ (row&7)
#pragma unroll
    for (int s = 0; s < 2; ++s) {
      int c = t + 256 * s;
      int row = c >> 3;
      int go = ((c & 7) ^ (row & 7)) * 16;
      async16(&Aq[(size_t)(rowBase + row) * KP + kb + go], &As[c * 16]);
    }
    // stage B: 2048 chunks (rows 0..255), 8 per thread
#pragma unroll
    for (int s = 0; s < 8; ++s) {
      int c = t + 256 * s;
      int row = c >> 3;
      int go = ((c & 7) ^ (row & 7)) * 16;
      async16(&W1q[(size_t)(colBase + row) * KP + kb + go], &Bs[c * 16]);
    }
    __syncthreads();
#pragma unroll
    for (int ks = 0; ks < 4; ++ks) {
      i32x4 av, bv[4];
      {
        int row = 32 * wr + m32;
        av = *(const i32x4*)&As[row * 128 + (((ks * 2 + kg) ^ (row & 7)) * 16)];
      }
#pragma unroll
      for (int tc = 0; tc < 4; ++tc) {
        int row = 128 * wc + 32 * tc + m32;
        bv[tc] = *(const i32x4*)&Bs[row * 128 + (((ks * 2 + kg) ^ (row & 7)) * 16)];
      }
#pragma unroll
      for (int tc = 0; tc < 4; ++tc)
        acc[tc] = __builtin_amdgcn_mfma_i32_32x32x32_i8(av, bv[tc], acc[tc], 0, 0, 0);
    }
  }

  // epilogue: store C1 (i16) + per-column partial sum/sumsq into LDS
#pragma unroll
  for (int tc = 0; tc < 4; ++tc) {
    const int colLoc = 128 * wc + 32 * tc + m32;
    const int col = colBase + colLoc;
    int s = 0, sq = 0;
#pragma unroll
    for (int rg = 0; rg < 16; ++rg) {
      int v = acc[tc][rg];
      int row = rowBase + 32 * wr + (rg & 3) + 8 * (rg >> 2) + 4 * kg;
      C1[(size_t)row * N1 + col] = (short)v;
      s += v;
      sq += v * v;  // <= 64 * 784^2 = 3.9e7 per column per block, fits int32
    }
    atomicAdd(&cS[colLoc], s);
    atomicAdd(&cQ[colLoc], sq);
  }
  __syncthreads();
  atomicAdd(&colsum[colBase + t], cS[t]);
  atomicAdd(&colsq[colBase + t], (ull)(unsigned)cQ[t]);
}

// Per-column integer ternary thresholds for z = fma(v,a,b):
// out = (w>=hi) - (w<=lo), w = sgn*v. Exact local search on the fma-evaluated boundary.
__device__ __forceinline__ void mk_thr(double a, double b, int& hi, int& lo, int8_t& sgn) {
  sgn = 1;
  if (a < 0.0) {
    a = -a;
    sgn = -1;  // z = (-v)*(-a) + b : monotone increasing in w=-v
  }
  if (a == 0.0) {
    double q = rint(b);
    if (q > 0.5) {
      hi = -1500;
      lo = -2000;
    } else if (q < -0.5) {
      hi = 2000;
      lo = 1500;
    } else {
      hi = 1500;
      lo = -1500;
    }
    return;
  }
  double g = (0.5 - b) / a;
  g = g > 1e6 ? 1e6 : (g < -1e6 ? -1e6 : g);
  if (g != g) g = 0.0;
  int c0 = (int)floor(g);
  c0 = c0 < -1400 ? -1400 : (c0 > 1400 ? 1400 : c0);
  for (int it = 0; it < 6 && fma((double)(c0 - 1), a, b) > 0.5; ++it) --c0;
  for (int it = 0; it < 6 && fma((double)c0, a, b) <= 0.5; ++it) ++c0;
  hi = c0 < -1500 ? -1500 : (c0 > 1500 ? 1500 : c0);
  double g2 = (-0.5 - b) / a;
  g2 = g2 > 1e6 ? 1e6 : (g2 < -1e6 ? -1e6 : g2);
  if (g2 != g2) g2 = 0.0;
  int c1 = (int)ceil(g2);
  c1 = c1 < -1400 ? -1400 : (c1 > 1400 ? 1400 : c1);
  for (int it = 0; it < 6 && fma((double)(c1 + 1), a, b) < -0.5; ++it) ++c1;
  for (int it = 0; it < 6 && fma((double)c1, a, b) >= -0.5; ++it) --c1;
  lo = c1 < -1500 ? -1500 : (c1 > 1500 ? 1500 : c1);
}

// K45: fused BN1-ternary (integer thresholds) + GEMM2 (i8 MFMA, wave=16x16 tile, K=1024)
// + C2 col stats. Thresholds computed in-block from colsum/colsq.
#define W2S 1040  // LDS row stride for W2 (2-way bank alias = free)
__global__ __launch_bounds__(256) void k45_bnq_gemm2(
    const short* __restrict__ C1, const int* __restrict__ colsum, const ull* __restrict__ colsq,
    const float* __restrict__ g1, const float* __restrict__ b1, const int8_t* __restrict__ W2q,
    short* __restrict__ C2, int* __restrict__ sum2p, ull* __restrict__ sq2p) {
  __shared__ int tpkS[N1];     // (hi<<16) | (lo & 0xffff)
  __shared__ int8_t sgnS[N1];  // per-column sign fold
  __shared__ int8_t W2s[16 * W2S];
  __shared__ int cS[16];
  __shared__ int cQ[16];
  const int t = threadIdx.x;
  for (int i = t; i < N1; i += 256) {
    double mean = (double)colsum[i] / 16384.0;
    double var = (double)colsq[i] / 16384.0 - mean * mean;
    double a = (double)g1[i] / sqrt(var + 1e-5);
    double b = (double)b1[i] - mean * a;
    int hi, lo;
    int8_t sg;
    mk_thr(a, b, hi, lo, sg);
    tpkS[i] = (hi << 16) | (lo & 0xffff);
    sgnS[i] = sg;
  }
  for (int i = t; i < 1024; i += 256) {  // 16KB of W2 as 16B chunks
    int r = i >> 6, c16 = (i & 63) * 16;
    *(int4*)&W2s[r * W2S + c16] = *(const int4*)&W2q[r * N1 + c16];
  }
  if (t < 16) {
    cS[t] = 0;
    cQ[t] = 0;
  }
  __syncthreads();

  const int lane = t & 63, wave = t >> 6;
  const int m = lane & 15, kc = lane >> 4;
  const int tile = blockIdx.x * 4 + wave;  // 0..1023
  const int rowBase = tile * 16;
  const short* arow = &C1[(size_t)(rowBase + m) * N1];

  i32x4 acc = {0, 0, 0, 0};
#pragma unroll
  for (int kt = 0; kt < 16; ++kt) {
    const int k0 = kt * 64 + kc * 16;
    s16x8 v0 = *(const s16x8*)&arow[k0];
    s16x8 v1 = *(const s16x8*)&arow[k0 + 8];
    union {
      int4 v[4];
      int w[16];
    } tps;
    tps.v[0] = *(const int4*)&tpkS[k0];
    tps.v[1] = *(const int4*)&tpkS[k0 + 4];
    tps.v[2] = *(const int4*)&tpkS[k0 + 8];
    tps.v[3] = *(const int4*)&tpkS[k0 + 12];
    union {
      int4 v;
      int8_t b[16];
    } sg;
    sg.v = *(const int4*)&sgnS[k0];
    union {
      i32x4 v;
      int8_t b[16];
    } afr;
#pragma unroll
    for (int j = 0; j < 8; ++j) {
      int tp = tps.w[j];
      int hi = tp >> 16, lo = (short)(tp & 0xffff);
      int w = (int)v0[j] * (int)sg.b[j];
      afr.b[j] = (int8_t)((w >= hi) - (w <= lo));
    }
#pragma unroll
    for (int j = 0; j < 8; ++j) {
      int tp = tps.w[8 + j];
      int hi = tp >> 16, lo = (short)(tp & 0xffff);
      int w = (int)v1[j] * (int)sg.b[8 + j];
      afr.b[8 + j] = (int8_t)((w >= hi) - (w <= lo));
    }
    i32x4 bfr = *(const i32x4*)&W2s[m * W2S + k0];
    acc = __builtin_amdgcn_mfma_i32_16x16x64_i8(afr.v, bfr, acc, 0, 0, 0);
  }

  // C/D layout: col = lane&15, row = (lane>>4)*4 + reg
  const int col = m;
#pragma unroll
  for (int rg = 0; rg < 4; ++rg) C2[(rowBase + kc * 4 + rg) * 16 + col] = (short)acc[rg];
  if (col < N2) {
    int s = 0, sq = 0;
#pragma unroll
    for (int rg = 0; rg < 4; ++rg) {
      int v = acc[rg];
      s += v;
      sq += v * v;
    }
    atomicAdd(&cS[col], s);
    atomicAdd(&cQ[col], sq);
  }
  __syncthreads();
  if (t < N2) {
    atomicAdd(&sum2p[t * 16], cS[t]);
    atomicAdd(&sq2p[t * 8], (ull)(unsigned)cQ[t]);
  }
}

// K7: t2 = ternary(batchnorm2(C2)) + global sum/sumsq of t2 (exact int).
__global__ __launch_bounds__(256) void k7_bn2q(const short* __restrict__ C2,
                                               const int* __restrict__ sum2p,
                                               const ull* __restrict__ sq2p,
                                               const float* __restrict__ g2,
                                               const float* __restrict__ b2,
                                               int8_t* __restrict__ t2, int* __restrict__ gsum,
                                               int* __restrict__ gsq) {
  __shared__ double meanS[N2], rsS[N2];
  if (threadIdx.x < N2) {
    int c = threadIdx.x;
    double mean = (double)sum2p[c * 16] / 16384.0;
    double var = (double)sq2p[c * 8] / 16384.0 - mean * mean;
    meanS[c] = mean;
    rsS[c] = sqrt(var + 1e-5);
  }
  __syncthreads();
  int s = 0, sq = 0;
  for (int id = blockIdx.x * 256 + threadIdx.x; id < NTOT; id += gridDim.x * 256) {
    int r = id / N2, c = id - r * N2;
    int v = C2[r * 16 + c];
    double z = ((double)v - meanS[c]) / rsS[c] * (double)g2[c] + (double)b2[c];
    double qq = rint(z);
    qq = qq < -1.0 ? -1.0 : (qq > 1.0 ? 1.0 : qq);
    int ti = (int)qq;
    t2[id] = (int8_t)ti;
    s += ti;
    sq += ti * ti;
  }
#pragma unroll
  for (int off = 32; off > 0; off >>= 1) {
    s += __shfl_xor(s, off, 64);
    sq += __shfl_xor(sq, off, 64);
  }
  __shared__ int bs, bq;
  if (threadIdx.x == 0) {
    bs = 0;
    bq = 0;
  }
  __syncthreads();
  if ((threadIdx.x & 63) == 0) {
    atomicAdd(&bs, s);
    atomicAdd(&bq, sq);
  }
  __syncthreads();
  if (threadIdx.x == 0) {
    atomicAdd(gsum, bs);
    atomicAdd(gsq, bq);
  }
}

// K9: out = tensornorm(t2)  (unbiased var, eps=1e-4)
__global__ void k9_out(const int8_t* __restrict__ t2, const int* __restrict__ gsum,
                       const int* __restrict__ gsq, const float* __restrict__ tn_w,
                       const float* __restrict__ tn_b, float* __restrict__ out) {
  int id = blockIdx.x * 256 + threadIdx.x;
  double n = (double)NTOT;
  double sm = (double)*gsum;
  double mean = sm / n;
  double var = ((double)*gsq - sm * sm / n) / (n - 1.0);
  double alpha = (double)tn_w[0] / sqrt(var + 1e-4);
  out[id] = (float)(((double)t2[id] - mean) * alpha + (double)tn_b[0]);
}

extern "C" void kernel_launch(void* const* d_in, const int* in_sizes, int n_in, void* d_out,
                              int out_size, void* d_ws, size_t ws_size, hipStream_t stream) {
  const float* x = (const float*)d_in[0];
  const float* W1 = (const float*)d_in[1];
  const float* g1 = (const float*)d_in[2];
  const float* b1 = (const float*)d_in[3];
  const float* W2 = (const float*)d_in[4];
  const float* g2 = (const float*)d_in[5];
  const float* b2 = (const float*)d_in[6];
  const float* tnw = (const float*)d_in[7];
  const float* tnb = (const float*)d_in[8];

  char* ws = (char*)d_ws;
  int8_t* Aq = (int8_t*)(ws + OFF_AQ);
  int8_t* W1q = (int8_t*)(ws + OFF_W1Q);
  int8_t* W2q = (int8_t*)(ws + OFF_W2Q);
  short* C1 = (short*)(ws + OFF_C1);
  int* statsZ = (int*)(ws + OFF_STATS);
  int* colsum = (int*)(ws + OFF_STATS);
  ull* colsq = (ull*)(ws + OFF_STATS + 4096);
  int* sum2p = (int*)(ws + OFF_STATS + 12288);
  ull* sq2p = (ull*)(ws + OFF_STATS + 13312);
  int* gsum = (int*)(ws + OFF_STATS + 14336);
  int* gsq = (int*)(ws + OFF_STATS + 14400);
  short* C2 = (short*)(ws + OFF_C2);
  int8_t* t2 = (int8_t*)(ws + OFF_T2);

  const int totalT = BB * KP / 16 + N1 * KP / 16 + N2 * N1 / 16;  // 975488
  k0_quant<<<(totalT + 255) / 256, 256, 0, stream>>>(x, W1, W2, Aq, W1q, W2q, statsZ);
  k1_gemm1<<<dim3(4, 256), 256, 0, stream>>>(Aq, W1q, C1, colsum, colsq);
  k45_bnq_gemm2<<<256, 256, 0, stream>>>(C1, colsum, colsq, g1, b1, W2q, C2, sum2p, sq2p);
  k7_bn2q<<<160, 256, 0, stream>>>(C2, sum2p, sq2p, g2, b2, t2, gsum, gsq);
  k9_out<<<NTOT / 256, 256, 0, stream>>>(t2, gsum, gsq, tnw, tnb, (float*)d_out);
}

// Round 9
// 152.358 us; speedup vs baseline: 1.0062x; 1.0062x over previous
//
#include <hip/hip_runtime.h>
#include <stdint.h>

typedef int i32x4 __attribute__((ext_vector_type(4)));
typedef int i32x16 __attribute__((ext_vector_type(16)));
typedef short s16x8 __attribute__((ext_vector_type(8)));
typedef unsigned long long ull;

#define BB 16384
#define KD 784
#define KP 896  // padded to multiple of 128 (BK=128)
#define N1 1024
#define N2 10
#define NTOT (BB * N2)  // 163840

// ---- workspace layout (bytes) ----
#define OFF_AQ 0ULL
#define SZ_AQ (14680064ULL)  // 16384*896 i8
#define OFF_W1Q (OFF_AQ + SZ_AQ)
#define SZ_W1Q (917504ULL)  // 1024*896 i8
#define OFF_W2Q (OFF_W1Q + SZ_W1Q)
#define SZ_W2Q (16384ULL)  // 16*1024 i8 (rows 10..15 poison; masked downstream)
#define OFF_C1 (OFF_W2Q + SZ_W2Q)
#define SZ_C1 (33554432ULL)  // 16384*1024 i16
#define OFF_STATS (OFF_C1 + SZ_C1)
#define SZ_STATS (16384ULL)
// stats sublayout (bytes): colsum int[1024] @0; colsq ull[1024] @4096;
//   sum2p int stride 16 ints (64B), 16 entries @12288;
//   sq2p  ull stride 8 ulls (64B), 16 entries @13312;
//   gsum int @14336; gsq int @14400  (separate cache lines)
#define OFF_C2 (OFF_STATS + SZ_STATS)
#define SZ_C2 (524288ULL)  // 16384*16 i16 (padded cols)
#define OFF_T2 (OFF_C2 + SZ_C2)
#define SZ_T2 (163840ULL)  // i8

__device__ __forceinline__ void async16(const void* g, void* l) {
  __builtin_amdgcn_global_load_lds((__attribute__((address_space(1))) void*)(void*)(g),
                                   (__attribute__((address_space(3))) void*)(l), 16, 0, 0);
}

__device__ __forceinline__ int8_t ternq(float v) {
  float q = rintf(v);
  return q > 0.5f ? 1 : (q < -0.5f ? -1 : 0);
}

// K0: quantize x -> Aq (i8, K padded to 896), W1 -> W1q, W2 -> W2q; zero stats region.
__global__ void k0_quant(const float* __restrict__ x, const float* __restrict__ W1,
                         const float* __restrict__ W2, int8_t* __restrict__ Aq,
                         int8_t* __restrict__ W1q, int8_t* __restrict__ W2q,
                         int* __restrict__ stats) {
  const int TA = BB * KP / 16;  // 917504
  const int TW = N1 * KP / 16;  // 57344
  const int T2 = N2 * N1 / 16;  // 640
  int tid = blockIdx.x * 256 + threadIdx.x;
  if (tid < 4096) stats[tid] = 0;  // 16KB stats zeroed (runs before k1 in stream order)
  union {
    int4 v;
    int8_t b[16];
  } o;
  o.v = make_int4(0, 0, 0, 0);
  if (tid < TA) {
    int base = tid * 16;
    int r = base / KP, k = base - r * KP;
    if (k < KD) {
      const float4* xp = (const float4*)&x[r * KD + k];
#pragma unroll
      for (int g = 0; g < 4; ++g) {
        float4 f = xp[g];
        o.b[g * 4 + 0] = ternq(2.0f * f.x - 1.0f);
        o.b[g * 4 + 1] = ternq(2.0f * f.y - 1.0f);
        o.b[g * 4 + 2] = ternq(2.0f * f.z - 1.0f);
        o.b[g * 4 + 3] = ternq(2.0f * f.w - 1.0f);
      }
    }
    *(int4*)&Aq[base] = o.v;
  } else if (tid < TA + TW) {
    int base = (tid - TA) * 16;
    int r = base / KP, k = base - r * KP;
    if (k < KD) {
      const float4* wp = (const float4*)&W1[r * KD + k];
#pragma unroll
      for (int g = 0; g < 4; ++g) {
        float4 f = wp[g];
        o.b[g * 4 + 0] = ternq(f.x);
        o.b[g * 4 + 1] = ternq(f.y);
        o.b[g * 4 + 2] = ternq(f.z);
        o.b[g * 4 + 3] = ternq(f.w);
      }
    }
    *(int4*)&W1q[base] = o.v;
  } else if (tid < TA + TW + T2) {
    int base = (tid - TA - TW) * 16;
    const float4* wp = (const float4*)&W2[base];
#pragma unroll
    for (int g = 0; g < 4; ++g) {
      float4 f = wp[g];
      o.b[g * 4 + 0] = ternq(f.x);
      o.b[g * 4 + 1] = ternq(f.y);
      o.b[g * 4 + 2] = ternq(f.z);
      o.b[g * 4 + 3] = ternq(f.w);
    }
    *(int4*)&W2q[base] = o.v;
  }
}

// K1: C1 = Aq @ W1q^T (128x128 tile, BK=128, i8 MFMA 32x32x32) + fused col stats.
// [R7 config — best measured. R8's 64x256 tile regressed: A re-fetch was LLC-absorbed,
//  so traffic cut bought nothing and wave balance worsened.]
// A/B frag: m=lane&31, k=(lane>>5)*16+j. C/D: col=lane&31,
// row=(reg&3)+8*(reg>>2)+4*(lane>>5)  [HW-verified, dtype-indep].
__global__ __launch_bounds__(256, 4) void k1_gemm1(const int8_t* __restrict__ Aq,
                                                   const int8_t* __restrict__ W1q,
                                                   short* __restrict__ C1,
                                                   int* __restrict__ colsum,
                                                   ull* __restrict__ colsq) {
  __shared__ int8_t As[128 * 128];
  __shared__ int8_t Bs[128 * 128];
  __shared__ int cS[128];
  __shared__ int cQ[128];
  const int t = threadIdx.x;
  const int lane = t & 63, wave = t >> 6;
  const int wr = wave >> 1, wc = wave & 1;
  const int rowBase = blockIdx.y * 128, colBase = blockIdx.x * 128;
  if (t < 128) {
    cS[t] = 0;
    cQ[t] = 0;
  }

  i32x16 acc[2][2] = {};
  const int m32 = lane & 31, kg = lane >> 5;

  // staging: chunk c = t + 256*s, s=0..3; row=c>>3, pos=c&7, granule g = pos ^ (row&7)
  int srow[4], sgo[4];
#pragma unroll
  for (int s = 0; s < 4; ++s) {
    int c = t + 256 * s;
    srow[s] = c >> 3;
    sgo[s] = ((c & 7) ^ (srow[s] & 7)) * 16;
  }

  for (int kt = 0; kt < 7; ++kt) {
    __syncthreads();
    const int kb = kt * 128;
#pragma unroll
    for (int s = 0; s < 4; ++s) {
      int c = t + 256 * s;
      async16(&Aq[(size_t)(rowBase + srow[s]) * KP + kb + sgo[s]], &As[c * 16]);
      async16(&W1q[(size_t)(colBase + srow[s]) * KP + kb + sgo[s]], &Bs[c * 16]);
    }
    __syncthreads();
#pragma unroll
    for (int ks = 0; ks < 4; ++ks) {
      i32x4 av[2], bv[2];
#pragma unroll
      for (int tr = 0; tr < 2; ++tr) {
        int row = 64 * wr + 32 * tr + m32;
        av[tr] = *(const i32x4*)&As[row * 128 + (((ks * 2 + kg) ^ (row & 7)) * 16)];
      }
#pragma unroll
      for (int tc = 0; tc < 2; ++tc) {
        int row = 64 * wc + 32 * tc + m32;
        bv[tc] = *(const i32x4*)&Bs[row * 128 + (((ks * 2 + kg) ^ (row & 7)) * 16)];
      }
#pragma unroll
      for (int tr = 0; tr < 2; ++tr)
#pragma unroll
        for (int tc = 0; tc < 2; ++tc)
          acc[tr][tc] =
              __builtin_amdgcn_mfma_i32_32x32x32_i8(av[tr], bv[tc], acc[tr][tc], 0, 0, 0);
    }
  }

  // epilogue: store C1 (i16) + per-column partial sum/sumsq into LDS
#pragma unroll
  for (int tc = 0; tc < 2; ++tc) {
    const int colLoc = 64 * wc + 32 * tc + m32;
    const int col = colBase + colLoc;
    int s = 0, sq = 0;
#pragma unroll
    for (int tr = 0; tr < 2; ++tr) {
#pragma unroll
      for (int rg = 0; rg < 16; ++rg) {
        int v = acc[tr][tc][rg];
        int row = rowBase + 64 * wr + 32 * tr + (rg & 3) + 8 * (rg >> 2) + 4 * kg;
        C1[(size_t)row * N1 + col] = (short)v;
        s += v;
        sq += v * v;  // <= 128 * 784^2 = 7.9e7, fits int32 per block
      }
    }
    atomicAdd(&cS[colLoc], s);
    atomicAdd(&cQ[colLoc], sq);
  }
  __syncthreads();
  if (t < 128) {
    atomicAdd(&colsum[colBase + t], cS[t]);
    atomicAdd(&colsq[colBase + t], (ull)(unsigned)cQ[t]);
  }
}

// Per-column integer ternary thresholds for z = fma(v,a,b):
// out = (w>=hi) - (w<=lo), w = sgn*v. Exact local search on the fma-evaluated boundary.
__device__ __forceinline__ void mk_thr(double a, double b, int& hi, int& lo, int8_t& sgn) {
  sgn = 1;
  if (a < 0.0) {
    a = -a;
    sgn = -1;  // z = (-v)*(-a) + b : monotone increasing in w=-v
  }
  if (a == 0.0) {
    double q = rint(b);
    if (q > 0.5) {
      hi = -1500;
      lo = -2000;
    } else if (q < -0.5) {
      hi = 2000;
      lo = 1500;
    } else {
      hi = 1500;
      lo = -1500;
    }
    return;
  }
  double g = (0.5 - b) / a;
  g = g > 1e6 ? 1e6 : (g < -1e6 ? -1e6 : g);
  if (g != g) g = 0.0;
  int c0 = (int)floor(g);
  c0 = c0 < -1400 ? -1400 : (c0 > 1400 ? 1400 : c0);
  for (int it = 0; it < 6 && fma((double)(c0 - 1), a, b) > 0.5; ++it) --c0;
  for (int it = 0; it < 6 && fma((double)c0, a, b) <= 0.5; ++it) ++c0;
  hi = c0 < -1500 ? -1500 : (c0 > 1500 ? 1500 : c0);
  double g2 = (-0.5 - b) / a;
  g2 = g2 > 1e6 ? 1e6 : (g2 < -1e6 ? -1e6 : g2);
  if (g2 != g2) g2 = 0.0;
  int c1 = (int)ceil(g2);
  c1 = c1 < -1400 ? -1400 : (c1 > 1400 ? 1400 : c1);
  for (int it = 0; it < 6 && fma((double)(c1 + 1), a, b) < -0.5; ++it) ++c1;
  for (int it = 0; it < 6 && fma((double)c1, a, b) >= -0.5; ++it) --c1;
  lo = c1 < -1500 ? -1500 : (c1 > 1500 ? 1500 : c1);
}

// K45: fused BN1-ternary (integer thresholds) + GEMM2 (i8 MFMA, wave=16x16 tile, K=1024)
// + C2 col stats. Thresholds computed in-block from colsum/colsq.
#define W2S 1040  // LDS row stride for W2 (2-way bank alias = free)
__global__ __launch_bounds__(256) void k45_bnq_gemm2(
    const short* __restrict__ C1, const int* __restrict__ colsum, const ull* __restrict__ colsq,
    const float* __restrict__ g1, const float* __restrict__ b1, const int8_t* __restrict__ W2q,
    short* __restrict__ C2, int* __restrict__ sum2p, ull* __restrict__ sq2p) {
  __shared__ int tpkS[N1];     // (hi<<16) | (lo & 0xffff)
  __shared__ int8_t sgnS[N1];  // per-column sign fold
  __shared__ int8_t W2s[16 * W2S];
  __shared__ int cS[16];
  __shared__ int cQ[16];
  const int t = threadIdx.x;
  for (int i = t; i < N1; i += 256) {
    double mean = (double)colsum[i] / 16384.0;
    double var = (double)colsq[i] / 16384.0 - mean * mean;
    double a = (double)g1[i] / sqrt(var + 1e-5);
    double b = (double)b1[i] - mean * a;
    int hi, lo;
    int8_t sg;
    mk_thr(a, b, hi, lo, sg);
    tpkS[i] = (hi << 16) | (lo & 0xffff);
    sgnS[i] = sg;
  }
  for (int i = t; i < 1024; i += 256) {  // 16KB of W2 as 16B chunks
    int r = i >> 6, c16 = (i & 63) * 16;
    *(int4*)&W2s[r * W2S + c16] = *(const int4*)&W2q[r * N1 + c16];
  }
  if (t < 16) {
    cS[t] = 0;
    cQ[t] = 0;
  }
  __syncthreads();

  const int lane = t & 63, wave = t >> 6;
  const int m = lane & 15, kc = lane >> 4;
  const int tile = blockIdx.x * 4 + wave;  // 0..1023
  const int rowBase = tile * 16;
  const short* arow = &C1[(size_t)(rowBase + m) * N1];

  i32x4 acc = {0, 0, 0, 0};
#pragma unroll
  for (int kt = 0; kt < 16; ++kt) {
    const int k0 = kt * 64 + kc * 16;
    s16x8 v0 = *(const s16x8*)&arow[k0];
    s16x8 v1 = *(const s16x8*)&arow[k0 + 8];
    union {
      int4 v[4];
      int w[16];
    } tps;
    tps.v[0] = *(const int4*)&tpkS[k0];
    tps.v[1] = *(const int4*)&tpkS[k0 + 4];
    tps.v[2] = *(const int4*)&tpkS[k0 + 8];
    tps.v[3] = *(const int4*)&tpkS[k0 + 12];
    union {
      int4 v;
      int8_t b[16];
    } sg;
    sg.v = *(const int4*)&sgnS[k0];
    union {
      i32x4 v;
      int8_t b[16];
    } afr;
#pragma unroll
    for (int j = 0; j < 8; ++j) {
      int tp = tps.w[j];
      int hi = tp >> 16, lo = (short)(tp & 0xffff);
      int w = (int)v0[j] * (int)sg.b[j];
      afr.b[j] = (int8_t)((w >= hi) - (w <= lo));
    }
#pragma unroll
    for (int j = 0; j < 8; ++j) {
      int tp = tps.w[8 + j];
      int hi = tp >> 16, lo = (short)(tp & 0xffff);
      int w = (int)v1[j] * (int)sg.b[8 + j];
      afr.b[8 + j] = (int8_t)((w >= hi) - (w <= lo));
    }
    i32x4 bfr = *(const i32x4*)&W2s[m * W2S + k0];
    acc = __builtin_amdgcn_mfma_i32_16x16x64_i8(afr.v, bfr, acc, 0, 0, 0);
  }

  // C/D layout: col = lane&15, row = (lane>>4)*4 + reg
  const int col = m;
#pragma unroll
  for (int rg = 0; rg < 4; ++rg) C2[(rowBase + kc * 4 + rg) * 16 + col] = (short)acc[rg];
  if (col < N2) {
    int s = 0, sq = 0;
#pragma unroll
    for (int rg = 0; rg < 4; ++rg) {
      int v = acc[rg];
      s += v;
      sq += v * v;
    }
    atomicAdd(&cS[col], s);
    atomicAdd(&cQ[col], sq);
  }
  __syncthreads();
  if (t < N2) {
    atomicAdd(&sum2p[t * 16], cS[t]);
    atomicAdd(&sq2p[t * 8], (ull)(unsigned)cQ[t]);
  }
}

// K7: t2 = ternary(batchnorm2(C2)) + global sum/sumsq of t2 (exact int).
__global__ __launch_bounds__(256) void k7_bn2q(const short* __restrict__ C2,
                                               const int* __restrict__ sum2p,
                                               const ull* __restrict__ sq2p,
                                               const float* __restrict__ g2,
                                               const float* __restrict__ b2,
                                               int8_t* __restrict__ t2, int* __restrict__ gsum,
                                               int* __restrict__ gsq) {
  __shared__ double meanS[N2], rsS[N2];
  if (threadIdx.x < N2) {
    int c = threadIdx.x;
    double mean = (double)sum2p[c * 16] / 16384.0;
    double var = (double)sq2p[c * 8] / 16384.0 - mean * mean;
    meanS[c] = mean;
    rsS[c] = sqrt(var + 1e-5);
  }
  __syncthreads();
  int s = 0, sq = 0;
  for (int id = blockIdx.x * 256 + threadIdx.x; id < NTOT; id += gridDim.x * 256) {
    int r = id / N2, c = id - r * N2;
    int v = C2[r * 16 + c];
    double z = ((double)v - meanS[c]) / rsS[c] * (double)g2[c] + (double)b2[c];
    double qq = rint(z);
    qq = qq < -1.0 ? -1.0 : (qq > 1.0 ? 1.0 : qq);
    int ti = (int)qq;
    t2[id] = (int8_t)ti;
    s += ti;
    sq += ti * ti;
  }
#pragma unroll
  for (int off = 32; off > 0; off >>= 1) {
    s += __shfl_xor(s, off, 64);
    sq += __shfl_xor(sq, off, 64);
  }
  __shared__ int bs, bq;
  if (threadIdx.x == 0) {
    bs = 0;
    bq = 0;
  }
  __syncthreads();
  if ((threadIdx.x & 63) == 0) {
    atomicAdd(&bs, s);
    atomicAdd(&bq, sq);
  }
  __syncthreads();
  if (threadIdx.x == 0) {
    atomicAdd(gsum, bs);
    atomicAdd(gsq, bq);
  }
}

// K9: out = tensornorm(t2)  (unbiased var, eps=1e-4)
__global__ void k9_out(const int8_t* __restrict__ t2, const int* __restrict__ gsum,
                       const int* __restrict__ gsq, const float* __restrict__ tn_w,
                       const float* __restrict__ tn_b, float* __restrict__ out) {
  int id = blockIdx.x * 256 + threadIdx.x;
  double n = (double)NTOT;
  double sm = (double)*gsum;
  double mean = sm / n;
  double var = ((double)*gsq - sm * sm / n) / (n - 1.0);
  double alpha = (double)tn_w[0] / sqrt(var + 1e-4);
  out[id] = (float)(((double)t2[id] - mean) * alpha + (double)tn_b[0]);
}

extern "C" void kernel_launch(void* const* d_in, const int* in_sizes, int n_in, void* d_out,
                              int out_size, void* d_ws, size_t ws_size, hipStream_t stream) {
  const float* x = (const float*)d_in[0];
  const float* W1 = (const float*)d_in[1];
  const float* g1 = (const float*)d_in[2];
  const float* b1 = (const float*)d_in[3];
  const float* W2 = (const float*)d_in[4];
  const float* g2 = (const float*)d_in[5];
  const float* b2 = (const float*)d_in[6];
  const float* tnw = (const float*)d_in[7];
  const float* tnb = (const float*)d_in[8];

  char* ws = (char*)d_ws;
  int8_t* Aq = (int8_t*)(ws + OFF_AQ);
  int8_t* W1q = (int8_t*)(ws + OFF_W1Q);
  int8_t* W2q = (int8_t*)(ws + OFF_W2Q);
  short* C1 = (short*)(ws + OFF_C1);
  int* statsZ = (int*)(ws + OFF_STATS);
  int* colsum = (int*)(ws + OFF_STATS);
  ull* colsq = (ull*)(ws + OFF_STATS + 4096);
  int* sum2p = (int*)(ws + OFF_STATS + 12288);
  ull* sq2p = (ull*)(ws + OFF_STATS + 13312);
  int* gsum = (int*)(ws + OFF_STATS + 14336);
  int* gsq = (int*)(ws + OFF_STATS + 14400);
  short* C2 = (short*)(ws + OFF_C2);
  int8_t* t2 = (int8_t*)(ws + OFF_T2);

  const int totalT = BB * KP / 16 + N1 * KP / 16 + N2 * N1 / 16;  // 975488
  k0_quant<<<(totalT + 255) / 256, 256, 0, stream>>>(x, W1, W2, Aq, W1q, W2q, statsZ);
  k1_gemm1<<<dim3(8, 128), 256, 0, stream>>>(Aq, W1q, C1, colsum, colsq);
  k45_bnq_gemm2<<<256, 256, 0, stream>>>(C1, colsum, colsq, g1, b1, W2q, C2, sum2p, sq2p);
  k7_bn2q<<<256, 256, 0, stream>>>(C2, sum2p, sq2p, g2, b2, t2, gsum, gsq);
  k9_out<<<NTOT / 256, 256, 0, stream>>>(t2, gsum, gsq, tnw, tnb, (float*)d_out);
}